// Round 3
// baseline (106.994 us; speedup 1.0000x reference)
//
#include <hip/hip_runtime.h>

typedef __attribute__((ext_vector_type(8))) short bf16x8;
typedef __attribute__((ext_vector_type(4))) float f32x4;

__device__ __forceinline__ unsigned short f2bf(float f) {
    unsigned u = __float_as_uint(f);
    unsigned r = (u + 0x7FFFu + ((u >> 16) & 1u)) >> 16;   // RNE
    return (unsigned short)r;
}

__device__ __forceinline__ void gload16(const unsigned short* g, unsigned short* l) {
    __builtin_amdgcn_global_load_lds((const __attribute__((address_space(1))) void*)g,
                                     (__attribute__((address_space(3))) void*)l, 16, 0, 0);
}

#define SCHED0() __builtin_amdgcn_sched_barrier(0)
#define BAR2()   do { SCHED0(); __builtin_amdgcn_s_barrier(); SCHED0(); } while (0)

// ---------------- conversion kernels ----------------

__global__ void conv_x_kernel(const float* __restrict__ x, unsigned short* __restrict__ xb, int total8) {
    int i = blockIdx.x * blockDim.x + threadIdx.x;
    if (i >= total8) return;
    const float4* xv = (const float4*)x;
    float4 a = xv[(size_t)i * 2];
    float4 b = xv[(size_t)i * 2 + 1];
    uint4 o;
    o.x = (unsigned)f2bf(a.x) | ((unsigned)f2bf(a.y) << 16);
    o.y = (unsigned)f2bf(a.z) | ((unsigned)f2bf(a.w) << 16);
    o.z = (unsigned)f2bf(b.x) | ((unsigned)f2bf(b.y) << 16);
    o.w = (unsigned)f2bf(b.z) | ((unsigned)f2bf(b.w) << 16);
    ((uint4*)xb)[i] = o;
}

__global__ void conv_c_kernel(const float* __restrict__ c, unsigned short* __restrict__ cb,
                              float* __restrict__ c2, int D) {
    int k = blockIdx.x;
    int tid = threadIdx.x;                      // 256 threads, 4 elems each
    const float4 v = ((const float4*)(c + (long)k * D))[tid];
    uint2 o;
    o.x = (unsigned)f2bf(v.x) | ((unsigned)f2bf(v.y) << 16);
    o.y = (unsigned)f2bf(v.z) | ((unsigned)f2bf(v.w) << 16);
    ((uint2*)(cb + (long)k * D))[tid] = o;
    float s = v.x * v.x + v.y * v.y + v.z * v.z + v.w * v.w;
    #pragma unroll
    for (int d = 1; d < 64; d <<= 1) s += __shfl_xor(s, d, 64);
    __shared__ float wsum[4];
    int lane = tid & 63, w = tid >> 6;
    if (lane == 0) wsum[w] = s;
    __syncthreads();
    if (tid == 0) c2[k] = wsum[0] + wsum[1] + wsum[2] + wsum[3];
}

__global__ void init_packed_kernel(unsigned long long* __restrict__ p, int n) {
    int i = blockIdx.x * blockDim.x + threadIdx.x;
    if (i < n) p[i] = ~0ull;
}

// ---------------- GEMM + argmin : 256x256 tile, BK=64, 8 waves, 8-phase ----------------
// LDS (128KB): A[2][256][64]bf16 at ushort idx buf*16384, B at 32768+buf*16384.
// Swizzle: 128B row, 16B slot q_phys = q_log ^ (row&7); linear LDS dest for
// global_load_lds, inverse-swizzled GLOBAL source, same XOR on ds_read (rule #21).
// Schedule per K-tile t (buf=t&1): ph1{dsA(m0-3)+dsB(n0-1); stage B(t+1)->buf^1; BAR;
// mfma m0-3 x n0-1; BAR} ph2{dsB(n2-3); BAR; mfma m0-3 x n2-3; BAR} ph3{dsA(m4-7);
// BAR; mfma m4-7 x n0-1; BAR} ph4{stage A(t+2)->buf; vmcnt(4); BAR; mfma m4-7 x
// n2-3; BAR}.  vmcnt(4) leaves exactly A(t+2) in flight => A(t+1),B(t+1) complete.
// Region safety: A(t+2) write lands after tile t's last buf-A read (ph3-end BAR);
// B(t+1) write after tile t-1's last buf^1-B read (its ph2).
__global__ void __launch_bounds__(512, 2)
gemm_argmin_kernel(const unsigned short* __restrict__ Xb,
                   const unsigned short* __restrict__ Cb,
                   const float* __restrict__ c2,
                   unsigned long long* __restrict__ packed,
                   int D, int nt) {
    __shared__ unsigned short sh[65536];       // 128 KiB
    const int tid  = threadIdx.x;
    const int lane = tid & 63;
    const int w    = tid >> 6;                 // 0..7
    const int wr   = w >> 2;                   // 0..1 : rows wr*128..+127
    const int wc   = w & 3;                    // 0..3 : cols wc*64..+63
    const long rowbase = (long)blockIdx.x * 256;
    const int  colbase = blockIdx.y * 256;

    const int fr = lane & 15;
    const int g  = lane >> 4;
    const int f7 = fr & 7;
    const int q0 = g ^ f7;                     // phys 16B slot for ks=0
    const int q1 = (4 + g) ^ f7;               // phys 16B slot for ks=1
    const int abase0 = (wr * 128 + fr) * 64;   // ushort idx within A buf
    const int bbase0 = 32768 + (wc * 64 + fr) * 64;

    f32x4 acc[8][4] = {};
    bf16x8 a[4][2], b[4][2];

    // ---- staging helpers (4 gload_lds per thread per call) ----
    auto stageA = [&](int kt, int buf) {
        unsigned short* base = sh + buf * 16384;
        const unsigned short* gsrc = Xb + rowbase * D + kt * 64;
        #pragma unroll
        for (int j = 0; j < 4; ++j) {
            int c = j * 512 + w * 64 + lane;   // 16B chunk index 0..2047
            int r = c >> 3;
            int q = (c & 7) ^ (r & 7);
            gload16(gsrc + (long)r * D + q * 8, base + (j * 512 + w * 64) * 8);
        }
    };
    auto stageB = [&](int kt, int buf) {
        unsigned short* base = sh + 32768 + buf * 16384;
        const unsigned short* gsrc = Cb + (long)colbase * D + kt * 64;
        #pragma unroll
        for (int j = 0; j < 4; ++j) {
            int c = j * 512 + w * 64 + lane;
            int r = c >> 3;
            int q = (c & 7) ^ (r & 7);
            gload16(gsrc + (long)r * D + q * 8, base + (j * 512 + w * 64) * 8);
        }
    };

    // ---- prologue: A(0), B(0), A(1); wait till only A(1) in flight ----
    stageA(0, 0);
    stageB(0, 0);
    if (nt > 1) stageA(1, 1);
    asm volatile("s_waitcnt vmcnt(4)" ::: "memory");
    BAR2();

    for (int t = 0; t < nt; ++t) {
        const int buf = t & 1;
        const int ab = abase0 + buf * 16384;
        const int bb = bbase0 + buf * 16384;

        // ---- ph1 ----
        #pragma unroll
        for (int m = 0; m < 4; ++m) {
            a[m][0] = *(const bf16x8*)&sh[ab + m * 1024 + q0 * 8];
            a[m][1] = *(const bf16x8*)&sh[ab + m * 1024 + q1 * 8];
        }
        #pragma unroll
        for (int n = 0; n < 2; ++n) {
            b[n][0] = *(const bf16x8*)&sh[bb + n * 1024 + q0 * 8];
            b[n][1] = *(const bf16x8*)&sh[bb + n * 1024 + q1 * 8];
        }
        if (t < nt - 1) stageB(t + 1, buf ^ 1);
        BAR2();
        __builtin_amdgcn_s_setprio(1);
        #pragma unroll
        for (int m = 0; m < 4; ++m)
            #pragma unroll
            for (int n = 0; n < 2; ++n) {
                acc[m][n] = __builtin_amdgcn_mfma_f32_16x16x32_bf16(a[m][0], b[n][0], acc[m][n], 0, 0, 0);
                acc[m][n] = __builtin_amdgcn_mfma_f32_16x16x32_bf16(a[m][1], b[n][1], acc[m][n], 0, 0, 0);
            }
        __builtin_amdgcn_s_setprio(0);
        BAR2();

        // ---- ph2 ----
        #pragma unroll
        for (int n = 2; n < 4; ++n) {
            b[n][0] = *(const bf16x8*)&sh[bb + n * 1024 + q0 * 8];
            b[n][1] = *(const bf16x8*)&sh[bb + n * 1024 + q1 * 8];
        }
        BAR2();
        __builtin_amdgcn_s_setprio(1);
        #pragma unroll
        for (int m = 0; m < 4; ++m)
            #pragma unroll
            for (int n = 2; n < 4; ++n) {
                acc[m][n] = __builtin_amdgcn_mfma_f32_16x16x32_bf16(a[m][0], b[n][0], acc[m][n], 0, 0, 0);
                acc[m][n] = __builtin_amdgcn_mfma_f32_16x16x32_bf16(a[m][1], b[n][1], acc[m][n], 0, 0, 0);
            }
        __builtin_amdgcn_s_setprio(0);
        BAR2();

        // ---- ph3 ----
        #pragma unroll
        for (int m = 0; m < 4; ++m) {
            a[m][0] = *(const bf16x8*)&sh[ab + (m + 4) * 1024 + q0 * 8];
            a[m][1] = *(const bf16x8*)&sh[ab + (m + 4) * 1024 + q1 * 8];
        }
        BAR2();
        __builtin_amdgcn_s_setprio(1);
        #pragma unroll
        for (int m = 0; m < 4; ++m)
            #pragma unroll
            for (int n = 0; n < 2; ++n) {
                acc[m + 4][n] = __builtin_amdgcn_mfma_f32_16x16x32_bf16(a[m][0], b[n][0], acc[m + 4][n], 0, 0, 0);
                acc[m + 4][n] = __builtin_amdgcn_mfma_f32_16x16x32_bf16(a[m][1], b[n][1], acc[m + 4][n], 0, 0, 0);
            }
        __builtin_amdgcn_s_setprio(0);
        BAR2();

        // ---- ph4 ----
        if (t < nt - 2) {
            stageA(t + 2, buf);
            asm volatile("s_waitcnt vmcnt(4)" ::: "memory");
        } else if (t == nt - 2) {
            asm volatile("s_waitcnt vmcnt(0)" ::: "memory");
        }
        BAR2();
        __builtin_amdgcn_s_setprio(1);
        #pragma unroll
        for (int m = 0; m < 4; ++m)
            #pragma unroll
            for (int n = 2; n < 4; ++n) {
                acc[m + 4][n] = __builtin_amdgcn_mfma_f32_16x16x32_bf16(a[m][0], b[n][0], acc[m + 4][n], 0, 0, 0);
                acc[m + 4][n] = __builtin_amdgcn_mfma_f32_16x16x32_bf16(a[m][1], b[n][1], acc[m + 4][n], 0, 0, 0);
            }
        __builtin_amdgcn_s_setprio(0);
        BAR2();
    }

    // ---- argmin epilogue: score = c2[k] - 2*dot ----
    float c2v[4];
    int   kcol[4];
    #pragma unroll
    for (int n = 0; n < 4; ++n) {
        kcol[n] = colbase + wc * 64 + n * 16 + fr;
        c2v[n]  = c2[kcol[n]];
    }
    #pragma unroll
    for (int m = 0; m < 8; ++m) {
        #pragma unroll
        for (int reg = 0; reg < 4; ++reg) {
            unsigned long long best = ~0ull;
            #pragma unroll
            for (int n = 0; n < 4; ++n) {
                float score = c2v[n] - 2.0f * acc[m][n][reg];
                unsigned u = __float_as_uint(score);
                u ^= (u >> 31) ? 0xFFFFFFFFu : 0x80000000u;   // order-preserving map
                unsigned long long cand = ((unsigned long long)u << 32) | (unsigned)kcol[n];
                best = cand < best ? cand : best;
            }
            #pragma unroll
            for (int s = 1; s < 16; s <<= 1) {
                unsigned long long other = __shfl_xor(best, s, 64);
                best = other < best ? other : best;
            }
            if (fr == 0) {
                long row = rowbase + wr * 128 + m * 16 + g * 4 + reg;
                atomicMin(&packed[row], best);   // min is order-independent -> deterministic
            }
        }
    }
}

// ---------------- segmented sum: sliced partials (S=8, labels fused) ----------------
__global__ void segsum_partial_kernel(const unsigned long long* __restrict__ packed,
                                      const float* __restrict__ emb,
                                      float* __restrict__ partial,
                                      int* __restrict__ pcount,
                                      int N, int D) {
    const int k   = blockIdx.x;
    const int s   = blockIdx.y;
    const int tid = threadIdx.x;          // 0..1023
    const int grp = tid >> 8;             // row-group 0..3
    const int ct  = tid & 255;            // col-thread: owns cols ct*4..ct*4+3
    const int lane = tid & 63, w = tid >> 6;

    __shared__ int idxbuf[2048];
    __shared__ int cnts[16];
    __shared__ float4 red[4][256];

    const int slice = N >> 3;             // 2048
    const int base0 = s * slice;
    int total = 0;
    for (int base = base0; base < base0 + slice; base += 1024) {
        const int n = base + tid;
        const bool m = ((unsigned)(packed[n] & 0xFFFFFFFFull) == (unsigned)k);
        const unsigned long long bal = __ballot(m);
        if (lane == 0) cnts[w] = (int)__popcll(bal);
        __syncthreads();
        int myoff = total, run = total;
        #pragma unroll
        for (int w2 = 0; w2 < 16; ++w2) {
            if (w2 == w) myoff = run;
            run += cnts[w2];
        }
        if (m) idxbuf[myoff + (int)__popcll(bal & ((1ull << lane) - 1ull))] = n;
        total = run;
        __syncthreads();
    }

    float4 acc = {0.f, 0.f, 0.f, 0.f};
    for (int j = grp; j < total; j += 4) {
        const int row = idxbuf[j];
        const float4 v = *(const float4*)(emb + (long)row * D + ct * 4);
        acc.x += v.x; acc.y += v.y; acc.z += v.z; acc.w += v.w;
    }
    red[grp][ct] = acc;
    __syncthreads();
    if (grp == 0) {
        float4 r = red[0][ct];
        #pragma unroll
        for (int q = 1; q < 4; ++q) {
            const float4 v = red[q][ct];
            r.x += v.x; r.y += v.y; r.z += v.z; r.w += v.w;
        }
        *(float4*)(partial + ((long)(k * 8 + s)) * D + ct * 4) = r;
    }
    if (tid == 0) pcount[k * 8 + s] = total;
}

// one block per cluster: reduce 8 slice partials (fixed order) + EMA finalize
__global__ void finalize_kernel(const float* __restrict__ partial,
                                const int* __restrict__ pcount,
                                const float* __restrict__ centers,
                                const int* __restrict__ cnt,
                                float* __restrict__ out, int D) {
    const int k = blockIdx.x;
    const int ct = threadIdx.x;           // 256 threads, 4 cols each
    float4 acc = {0.f, 0.f, 0.f, 0.f};
    int mtot = 0;
    #pragma unroll
    for (int s = 0; s < 8; ++s) {
        const float4 p = *(const float4*)(partial + ((long)(k * 8 + s)) * D + ct * 4);
        acc.x += p.x; acc.y += p.y; acc.z += p.z; acc.w += p.w;
        mtot += pcount[k * 8 + s];
    }
    const float4 cv = *(const float4*)(centers + (long)k * D + ct * 4);
    float4 o;
    if (mtot > 0) {
        float ccn = 0.5f * (float)cnt[k] + 0.5f * (float)mtot;
        float lr  = 1.0f / (ccn + 1.0f);
        float im  = 1.0f / (float)mtot;
        float om  = 1.0f - lr;
        o.x = om * cv.x + lr * (acc.x * im);
        o.y = om * cv.y + lr * (acc.y * im);
        o.z = om * cv.z + lr * (acc.z * im);
        o.w = om * cv.w + lr * (acc.w * im);
    } else {
        o = cv;
    }
    *(float4*)(out + (long)k * D + ct * 4) = o;
}

// ---------------- launch ----------------

extern "C" void kernel_launch(void* const* d_in, const int* in_sizes, int n_in,
                              void* d_out, int out_size, void* d_ws, size_t ws_size,
                              hipStream_t stream) {
    const float* emb = (const float*)d_in[0];
    const float* cen = (const float*)d_in[1];
    const int*   cnt = (const int*)d_in[2];
    float* out = (float*)d_out;
    const int K = in_sizes[2];
    const int D = in_sizes[1] / K;      // 1024
    const int N = in_sizes[0] / D;      // 16384

    char* ws = (char*)d_ws;
    size_t xb_bytes = (size_t)N * D * 2;            // 32 MB
    size_t cb_bytes = (size_t)K * D * 2;            // 2 MB
    unsigned short* Xb = (unsigned short*)ws;
    unsigned short* Cb = (unsigned short*)(ws + xb_bytes);
    float* c2 = (float*)(ws + xb_bytes + cb_bytes);
    unsigned long long* packed = (unsigned long long*)(ws + xb_bytes + cb_bytes + (size_t)K * 4);
    // partial sums alias the Xb region (dead after gemm); K*8*D*4 = 32 MB exactly.
    float* partial = (float*)ws;
    int* pcount = (int*)(ws + xb_bytes + cb_bytes + (size_t)K * 4 + (size_t)N * 8);

    int total8 = N * D / 8;
    conv_x_kernel<<<dim3((total8 + 255) / 256), dim3(256), 0, stream>>>(emb, Xb, total8);
    conv_c_kernel<<<dim3(K), dim3(256), 0, stream>>>(cen, Cb, c2, D);
    init_packed_kernel<<<dim3((N + 255) / 256), dim3(256), 0, stream>>>(packed, N);
    gemm_argmin_kernel<<<dim3(N / 256, K / 256), dim3(512), 0, stream>>>(Xb, Cb, c2, packed, D, D / 64);
    segsum_partial_kernel<<<dim3(K, 8), dim3(1024), 0, stream>>>(packed, emb, partial, pcount, N, D);
    finalize_kernel<<<dim3(K), dim3(256), 0, stream>>>(partial, pcount, cen, cnt, out, D);
}

// Round 4
// 101.053 us; speedup vs baseline: 1.0588x; 1.0588x over previous
//
#include <hip/hip_runtime.h>

typedef __attribute__((ext_vector_type(8))) short bf16x8;
typedef __attribute__((ext_vector_type(4))) float f32x4;

__device__ __forceinline__ unsigned short f2bf(float f) {
    unsigned u = __float_as_uint(f);
    unsigned r = (u + 0x7FFFu + ((u >> 16) & 1u)) >> 16;   // RNE
    return (unsigned short)r;
}

__device__ __forceinline__ void gload16(const unsigned short* g, unsigned short* l) {
    __builtin_amdgcn_global_load_lds((const __attribute__((address_space(1))) void*)g,
                                     (__attribute__((address_space(3))) void*)l, 16, 0, 0);
}

// compile-time memory fence + HW barrier + fence: orders memory ops across the
// barrier without pinning instruction scheduling (m141 lesson).
#define BARRIER() do { asm volatile("" ::: "memory"); __builtin_amdgcn_s_barrier(); asm volatile("" ::: "memory"); } while (0)

// ---------------- conversion kernels ----------------

__global__ void conv_x_kernel(const float* __restrict__ x, unsigned short* __restrict__ xb, int total8) {
    int i = blockIdx.x * blockDim.x + threadIdx.x;
    if (i >= total8) return;
    const float4* xv = (const float4*)x;
    float4 a = xv[(size_t)i * 2];
    float4 b = xv[(size_t)i * 2 + 1];
    uint4 o;
    o.x = (unsigned)f2bf(a.x) | ((unsigned)f2bf(a.y) << 16);
    o.y = (unsigned)f2bf(a.z) | ((unsigned)f2bf(a.w) << 16);
    o.z = (unsigned)f2bf(b.x) | ((unsigned)f2bf(b.y) << 16);
    o.w = (unsigned)f2bf(b.z) | ((unsigned)f2bf(b.w) << 16);
    ((uint4*)xb)[i] = o;
}

// one block per center row: bf16 convert + exact fp32 ||c||^2 + packed-init (fused)
__global__ void conv_c_kernel(const float* __restrict__ c, unsigned short* __restrict__ cb,
                              float* __restrict__ c2, unsigned long long* __restrict__ packed,
                              int N, int D) {
    int k = blockIdx.x;
    int tid = threadIdx.x;                      // 256 threads, 4 elems each
    const float4 v = ((const float4*)(c + (long)k * D))[tid];
    uint2 o;
    o.x = (unsigned)f2bf(v.x) | ((unsigned)f2bf(v.y) << 16);
    o.y = (unsigned)f2bf(v.z) | ((unsigned)f2bf(v.w) << 16);
    ((uint2*)(cb + (long)k * D))[tid] = o;
    float s = v.x * v.x + v.y * v.y + v.z * v.z + v.w * v.w;
    #pragma unroll
    for (int d = 1; d < 64; d <<= 1) s += __shfl_xor(s, d, 64);
    __shared__ float wsum[4];
    int lane = tid & 63, w = tid >> 6;
    if (lane == 0) wsum[w] = s;
    __syncthreads();
    if (tid == 0) c2[k] = wsum[0] + wsum[1] + wsum[2] + wsum[3];
    int gid = k * 256 + tid;
    if (gid < N) packed[gid] = ~0ull;
}

// ---------------- GEMM + argmin : 256x256 tile, BK=64, 8 waves ----------------
// 4 barriers/tile, one-tile-ahead staging, full vmcnt drain at ph4 (issue-to-wait
// gap ~3 windows >> HBM latency, so the drain is cheap).  Window audit:
//  W1=[BAR4(t-1),BAR1(t)): reads b01(t) from p-B; stages A(t+1),B(t+1)->p^1. disjoint.
//  W2=[BAR1,BAR2): reads a03(t) p-A, b23(t) p-B; in-flight writes -> p^1. disjoint.
//  W3=[BAR2,BAR3): MFMA only.
//  W4=[BAR3,BAR4): reads a47(t) p-A; in-flight writes -> p^1. disjoint.
// Stage->p^1 lands before anyone reads p^1: vmcnt(0) pre-BAR4 + BAR4.
// Last reads of a region always >=1 barrier before its re-stage (audited above).
__global__ void __launch_bounds__(512, 2)
gemm_argmin_kernel(const unsigned short* __restrict__ Xb,
                   const unsigned short* __restrict__ Cb,
                   const float* __restrict__ c2,
                   unsigned long long* __restrict__ packed,
                   int D, int nt) {
    __shared__ unsigned short sh[65536];       // 128 KiB: A[2][256][64] | B[2][256][64]
    const int tid  = threadIdx.x;
    const int lane = tid & 63;
    const int w    = tid >> 6;                 // 0..7
    const int wr   = w >> 2;                   // 0..1 : rows wr*128..+127
    const int wc   = w & 3;                    // 0..3 : cols wc*64..+63
    const long rowbase = (long)blockIdx.x * 256;
    const int  colbase = blockIdx.y * 256;

    const int fr = lane & 15;
    const int g  = lane >> 4;
    const int f7 = fr & 7;
    const int q0 = g ^ f7;                     // phys 16B slot for ks=0
    const int q1 = (4 + g) ^ f7;               // phys 16B slot for ks=1
    const int abase0 = (wr * 128 + fr) * 64;   // ushort idx within A buf
    const int bbase0 = 32768 + (wc * 64 + fr) * 64;

    f32x4 acc[8][4] = {};
    bf16x8 a[4][2], b[4][2];

    auto stageA = [&](int kt, int buf) {
        unsigned short* base = sh + buf * 16384;
        const unsigned short* gsrc = Xb + rowbase * D + kt * 64;
        #pragma unroll
        for (int j = 0; j < 4; ++j) {
            int c = j * 512 + w * 64 + lane;   // 16B chunk index 0..2047
            int r = c >> 3;
            int q = (c & 7) ^ (r & 7);
            gload16(gsrc + (long)r * D + q * 8, base + (j * 512 + w * 64) * 8);
        }
    };
    auto stageB = [&](int kt, int buf) {
        unsigned short* base = sh + 32768 + buf * 16384;
        const unsigned short* gsrc = Cb + (long)colbase * D + kt * 64;
        #pragma unroll
        for (int j = 0; j < 4; ++j) {
            int c = j * 512 + w * 64 + lane;
            int r = c >> 3;
            int q = (c & 7) ^ (r & 7);
            gload16(gsrc + (long)r * D + q * 8, base + (j * 512 + w * 64) * 8);
        }
    };

    // ---- prologue ----
    stageA(0, 0);
    stageB(0, 0);
    asm volatile("s_waitcnt vmcnt(0)" ::: "memory");
    BARRIER();
    {   // b01(0) from buf0
        const int bb = bbase0;
        #pragma unroll
        for (int n = 0; n < 2; ++n) {
            b[n][0] = *(const bf16x8*)&sh[bb + n * 1024 + q0 * 8];
            b[n][1] = *(const bf16x8*)&sh[bb + n * 1024 + q1 * 8];
        }
    }

    for (int t = 0; t < nt; ++t) {
        const int p  = t & 1;
        const int ab = abase0 + p * 16384;
        const int bb = bbase0 + p * 16384;
        const int bbn = bbase0 + (p ^ 1) * 16384;

        // ---- W1 tail: stage next tile (writes p^1; this window reads only p) ----
        if (t < nt - 1) { stageA(t + 1, p ^ 1); stageB(t + 1, p ^ 1); }
        BARRIER();  // BAR1

        // ---- W2: read a03 + b23 (from p), MFMA m0-3 x n0-1 ----
        #pragma unroll
        for (int m = 0; m < 4; ++m) {
            a[m][0] = *(const bf16x8*)&sh[ab + m * 1024 + q0 * 8];
            a[m][1] = *(const bf16x8*)&sh[ab + m * 1024 + q1 * 8];
        }
        #pragma unroll
        for (int n = 2; n < 4; ++n) {
            b[n][0] = *(const bf16x8*)&sh[bb + n * 1024 + q0 * 8];
            b[n][1] = *(const bf16x8*)&sh[bb + n * 1024 + q1 * 8];
        }
        __builtin_amdgcn_s_setprio(1);
        #pragma unroll
        for (int m = 0; m < 4; ++m)
            #pragma unroll
            for (int n = 0; n < 2; ++n) {
                acc[m][n] = __builtin_amdgcn_mfma_f32_16x16x32_bf16(a[m][0], b[n][0], acc[m][n], 0, 0, 0);
                acc[m][n] = __builtin_amdgcn_mfma_f32_16x16x32_bf16(a[m][1], b[n][1], acc[m][n], 0, 0, 0);
            }
        __builtin_amdgcn_s_setprio(0);
        BARRIER();  // BAR2

        // ---- W3: MFMA m0-3 x n2-3 ----
        __builtin_amdgcn_s_setprio(1);
        #pragma unroll
        for (int m = 0; m < 4; ++m)
            #pragma unroll
            for (int n = 2; n < 4; ++n) {
                acc[m][n] = __builtin_amdgcn_mfma_f32_16x16x32_bf16(a[m][0], b[n][0], acc[m][n], 0, 0, 0);
                acc[m][n] = __builtin_amdgcn_mfma_f32_16x16x32_bf16(a[m][1], b[n][1], acc[m][n], 0, 0, 0);
            }
        __builtin_amdgcn_s_setprio(0);
        BARRIER();  // BAR3

        // ---- W4: read a47 (into a[] regs, WAR ok), MFMA m4-7 x n0-1 ----
        #pragma unroll
        for (int m = 0; m < 4; ++m) {
            a[m][0] = *(const bf16x8*)&sh[ab + (m + 4) * 1024 + q0 * 8];
            a[m][1] = *(const bf16x8*)&sh[ab + (m + 4) * 1024 + q1 * 8];
        }
        __builtin_amdgcn_s_setprio(1);
        #pragma unroll
        for (int m = 0; m < 4; ++m)
            #pragma unroll
            for (int n = 0; n < 2; ++n) {
                acc[m + 4][n] = __builtin_amdgcn_mfma_f32_16x16x32_bf16(a[m][0], b[n][0], acc[m + 4][n], 0, 0, 0);
                acc[m + 4][n] = __builtin_amdgcn_mfma_f32_16x16x32_bf16(a[m][1], b[n][1], acc[m + 4][n], 0, 0, 0);
            }
        __builtin_amdgcn_s_setprio(0);
        if (t < nt - 1) asm volatile("s_waitcnt vmcnt(0)" ::: "memory");
        BARRIER();  // BAR4

        // ---- W1 head of next tile: read b01(t+1) from p^1 (no consumer here
        //      -> overlaps the MFMA below), MFMA m4-7 x n2-3 ----
        if (t < nt - 1) {
            #pragma unroll
            for (int n = 0; n < 2; ++n) {
                b[n][0] = *(const bf16x8*)&sh[bbn + n * 1024 + q0 * 8];
                b[n][1] = *(const bf16x8*)&sh[bbn + n * 1024 + q1 * 8];
            }
        }
        __builtin_amdgcn_s_setprio(1);
        #pragma unroll
        for (int m = 0; m < 4; ++m)
            #pragma unroll
            for (int n = 2; n < 4; ++n) {
                acc[m + 4][n] = __builtin_amdgcn_mfma_f32_16x16x32_bf16(a[m][0], b[n][0], acc[m + 4][n], 0, 0, 0);
                acc[m + 4][n] = __builtin_amdgcn_mfma_f32_16x16x32_bf16(a[m][1], b[n][1], acc[m + 4][n], 0, 0, 0);
            }
        __builtin_amdgcn_s_setprio(0);
    }

    // ---- argmin epilogue: score = c2[k] - 2*dot.  C/D: col=lane&15, row=g*4+reg ----
    float c2v[4];
    int   kcol[4];
    #pragma unroll
    for (int n = 0; n < 4; ++n) {
        kcol[n] = colbase + wc * 64 + n * 16 + fr;
        c2v[n]  = c2[kcol[n]];
    }
    #pragma unroll
    for (int m = 0; m < 8; ++m) {
        #pragma unroll
        for (int reg = 0; reg < 4; ++reg) {
            unsigned long long best = ~0ull;
            #pragma unroll
            for (int n = 0; n < 4; ++n) {
                float score = c2v[n] - 2.0f * acc[m][n][reg];
                unsigned u = __float_as_uint(score);
                u ^= (u >> 31) ? 0xFFFFFFFFu : 0x80000000u;   // order-preserving map
                unsigned long long cand = ((unsigned long long)u << 32) | (unsigned)kcol[n];
                best = cand < best ? cand : best;
            }
            #pragma unroll
            for (int s = 1; s < 16; s <<= 1) {
                unsigned long long other = __shfl_xor(best, s, 64);
                best = other < best ? other : best;
            }
            if (fr == 0) {
                long row = rowbase + wr * 128 + m * 16 + g * 4 + reg;
                atomicMin(&packed[row], best);   // min is order-independent -> deterministic
            }
        }
    }
}

__global__ void extract16_kernel(const unsigned long long* __restrict__ p,
                                 unsigned short* __restrict__ lab, int n) {
    int i = blockIdx.x * blockDim.x + threadIdx.x;
    if (i < n) lab[i] = (unsigned short)(p[i] & 0xFFFFull);
}

// ---------------- segmented sum: sliced partials (S=4, u16 labels) ----------------
__global__ void segsum_partial_kernel(const unsigned short* __restrict__ lab,
                                      const float* __restrict__ emb,
                                      float* __restrict__ partial,
                                      int* __restrict__ pcount,
                                      int N, int D) {
    const int k   = blockIdx.x;
    const int s   = blockIdx.y;
    const int tid = threadIdx.x;          // 0..1023
    const int grp = tid >> 8;             // row-group 0..3
    const int ct  = tid & 255;            // col-thread: owns cols ct*4..ct*4+3
    const int lane = tid & 63, w = tid >> 6;

    __shared__ int idxbuf[4096];
    __shared__ int cnts[16];
    __shared__ float4 red[4][256];

    const int slice = N >> 2;             // 4096
    const int base0 = s * slice;
    int total = 0;
    for (int base = base0; base < base0 + slice; base += 1024) {
        const int n = base + tid;
        const bool m = (lab[n] == (unsigned short)k);
        const unsigned long long bal = __ballot(m);
        if (lane == 0) cnts[w] = (int)__popcll(bal);
        __syncthreads();
        int myoff = total, run = total;
        #pragma unroll
        for (int w2 = 0; w2 < 16; ++w2) {
            if (w2 == w) myoff = run;
            run += cnts[w2];
        }
        if (m) idxbuf[myoff + (int)__popcll(bal & ((1ull << lane) - 1ull))] = n;
        total = run;
        __syncthreads();
    }

    float4 acc = {0.f, 0.f, 0.f, 0.f};
    for (int j = grp; j < total; j += 4) {
        const int row = idxbuf[j];
        const float4 v = *(const float4*)(emb + (long)row * D + ct * 4);
        acc.x += v.x; acc.y += v.y; acc.z += v.z; acc.w += v.w;
    }
    red[grp][ct] = acc;
    __syncthreads();
    if (grp == 0) {
        float4 r = red[0][ct];
        #pragma unroll
        for (int q = 1; q < 4; ++q) {
            const float4 v = red[q][ct];
            r.x += v.x; r.y += v.y; r.z += v.z; r.w += v.w;
        }
        *(float4*)(partial + ((long)(k * 4 + s)) * D + ct * 4) = r;
    }
    if (tid == 0) pcount[k * 4 + s] = total;
}

// one block per cluster: reduce 4 slice partials (fixed order) + EMA finalize
__global__ void finalize_kernel(const float* __restrict__ partial,
                                const int* __restrict__ pcount,
                                const float* __restrict__ centers,
                                const int* __restrict__ cnt,
                                float* __restrict__ out, int D) {
    const int k = blockIdx.x;
    const int ct = threadIdx.x;           // 256 threads, 4 cols each
    float4 acc = {0.f, 0.f, 0.f, 0.f};
    int mtot = 0;
    #pragma unroll
    for (int s = 0; s < 4; ++s) {
        const float4 p = *(const float4*)(partial + ((long)(k * 4 + s)) * D + ct * 4);
        acc.x += p.x; acc.y += p.y; acc.z += p.z; acc.w += p.w;
        mtot += pcount[k * 4 + s];
    }
    const float4 cv = *(const float4*)(centers + (long)k * D + ct * 4);
    float4 o;
    if (mtot > 0) {
        float ccn = 0.5f * (float)cnt[k] + 0.5f * (float)mtot;
        float lr  = 1.0f / (ccn + 1.0f);
        float im  = 1.0f / (float)mtot;
        float om  = 1.0f - lr;
        o.x = om * cv.x + lr * (acc.x * im);
        o.y = om * cv.y + lr * (acc.y * im);
        o.z = om * cv.z + lr * (acc.z * im);
        o.w = om * cv.w + lr * (acc.w * im);
    } else {
        o = cv;
    }
    *(float4*)(out + (long)k * D + ct * 4) = o;
}

// ---------------- launch ----------------

extern "C" void kernel_launch(void* const* d_in, const int* in_sizes, int n_in,
                              void* d_out, int out_size, void* d_ws, size_t ws_size,
                              hipStream_t stream) {
    const float* emb = (const float*)d_in[0];
    const float* cen = (const float*)d_in[1];
    const int*   cnt = (const int*)d_in[2];
    float* out = (float*)d_out;
    const int K = in_sizes[2];
    const int D = in_sizes[1] / K;      // 1024
    const int N = in_sizes[0] / D;      // 16384

    char* ws = (char*)d_ws;
    size_t xb_bytes = (size_t)N * D * 2;            // 32 MB
    size_t cb_bytes = (size_t)K * D * 2;            // 2 MB
    unsigned short* Xb = (unsigned short*)ws;
    unsigned short* Cb = (unsigned short*)(ws + xb_bytes);
    float* c2 = (float*)(ws + xb_bytes + cb_bytes);
    unsigned long long* packed = (unsigned long long*)(ws + xb_bytes + cb_bytes + (size_t)K * 4);
    unsigned short* lab16 = (unsigned short*)(ws + xb_bytes + cb_bytes + (size_t)K * 4 + (size_t)N * 8);
    int* pcount = (int*)(ws + xb_bytes + cb_bytes + (size_t)K * 4 + (size_t)N * 8 + (size_t)N * 2);
    // partial sums alias the Xb region (dead after gemm); K*4*D*4 = 16 MB.
    float* partial = (float*)ws;

    int total8 = N * D / 8;
    conv_x_kernel<<<dim3((total8 + 255) / 256), dim3(256), 0, stream>>>(emb, Xb, total8);
    conv_c_kernel<<<dim3(K), dim3(256), 0, stream>>>(cen, Cb, c2, packed, N, D);
    gemm_argmin_kernel<<<dim3(N / 256, K / 256), dim3(512), 0, stream>>>(Xb, Cb, c2, packed, D, D / 64);
    extract16_kernel<<<dim3((N + 255) / 256), dim3(256), 0, stream>>>(packed, lab16, N);
    segsum_partial_kernel<<<dim3(K, 4), dim3(1024), 0, stream>>>(lab16, emb, partial, pcount, N, D);
    finalize_kernel<<<dim3(K), dim3(256), 0, stream>>>(partial, pcount, cen, cnt, out, D);
}